// Round 10
// baseline (273.505 us; speedup 1.0000x reference)
//
#include <hip/hip_runtime.h>

#define B_ 2
#define L_ 4096
#define D_ 256
#define W_ 128

typedef __bf16 bf16;
typedef __bf16 bf16x8 __attribute__((ext_vector_type(8)));
typedef __bf16 bf16x4 __attribute__((ext_vector_type(4)));
typedef float f32x4 __attribute__((ext_vector_type(4)));

#define MFMA16(a, b, c) __builtin_amdgcn_mfma_f32_16x16x32_bf16((a), (b), (c), 0, 0, 0)

__device__ __forceinline__ int imin(int a, int b) { return a < b ? a : b; }
__device__ __forceinline__ int imax(int a, int b) { return a > b ? a : b; }

// Split 8 consecutive f32 into hi/lo bf16 fragments (hi = rn(x), lo = rn(x-hi)).
__device__ __forceinline__ void split8(const float* p, bf16x8& hi, bf16x8& lo) {
  f32x4 v0 = ((const f32x4*)p)[0], v1 = ((const f32x4*)p)[1];
#pragma unroll
  for (int j = 0; j < 4; ++j) {
    bf16 h0 = (bf16)v0[j]; hi[j] = h0; lo[j] = (bf16)(v0[j] - (float)h0);
    bf16 h1 = (bf16)v1[j]; hi[j + 4] = h1; lo[j + 4] = (bf16)(v1[j] - (float)h1);
  }
}

// ---------------------------------------------------------------------------
// prep_zero: 2432 blocks x 256 threads. All parts independent; the 120 MB
// zero-fill's store BW hides every weight-prep latency.
//   [0,2048)    zero all out-of-band 16B slots of the f32 attn region
//               (block z handles rows [z*4, z*4+4) of one batch)
//   [2048,2176) transpose-split Wq / Wk -> bf16 hi/lo
//   [2176,2432) row i of Wc = Wv@Wo (f32, 8-way ILP), stored transposed-
//               split; i==0 also computes bc = bv@Wo + bo.
// ---------------------------------------------------------------------------
__global__ __launch_bounds__(256) void prep_zero(
    const float* __restrict__ Wq, const float* __restrict__ Wk,
    const float* __restrict__ Wv, const float* __restrict__ Wo,
    const float* __restrict__ bv, const float* __restrict__ bo,
    bf16* __restrict__ wqThi, bf16* __restrict__ wqTlo,
    bf16* __restrict__ wkThi, bf16* __restrict__ wkTlo,
    bf16* __restrict__ wcThi, bf16* __restrict__ wcTlo,
    float* __restrict__ bc, float* __restrict__ attn) {
  int blk = blockIdx.x;
  if (blk < 2048) {
    // 4 rows per block: rows [r0, r0+4) of batch b
    int b = blk >> 10;
    int r0 = (blk & 1023) * 4;
    f32x4 z = {0.f, 0.f, 0.f, 0.f};
    for (int rr = 0; rr < 4; ++rr) {
      int ig = r0 + rr;
      int slo = imax(0, ig - W_) >> 2;        // first 16B slot touching band
      int shi = imin(L_ - 1, ig + W_) >> 2;   // last
      float* arow = attn + (size_t)(b * L_ + ig) * L_;
      for (int s = threadIdx.x; s < L_ / 4; s += 256) {
        if (s < slo || s > shi)
          __builtin_nontemporal_store(z, (f32x4*)(arow + s * 4));
      }
    }
    return;
  }
  blk -= 2048;
  if (blk < 128) {
    int m = blk >> 6;  // 0: Wq, 1: Wk
    int t = blk & 63;
    int bx = t & 7, by = t >> 3;
    const float* src = m ? Wk : Wq;
    bf16* dh = m ? wkThi : wqThi;
    bf16* dl = m ? wkTlo : wqTlo;
    __shared__ float s[32][33];
    int c = threadIdx.x & 31, r0 = threadIdx.x >> 5;
    int br = by * 32, bcc = bx * 32;
    for (int rr = r0; rr < 32; rr += 8) s[rr][c] = src[(br + rr) * 256 + bcc + c];
    __syncthreads();
    for (int rr = r0; rr < 32; rr += 8) {
      float v = s[c][rr];
      bf16 h = (bf16)v;
      dh[(bcc + rr) * 256 + br + c] = h;
      dl[(bcc + rr) * 256 + br + c] = (bf16)(v - (float)h);
    }
    return;
  }
  int i = blk - 128, j = threadIdx.x;
  float acc[8] = {};
  for (int k0 = 0; k0 < 256; k0 += 8) {
#pragma unroll
    for (int t = 0; t < 8; ++t)
      acc[t] = fmaf(Wv[i * 256 + k0 + t], Wo[(k0 + t) * 256 + j], acc[t]);
  }
  float s = ((acc[0] + acc[1]) + (acc[2] + acc[3])) + ((acc[4] + acc[5]) + (acc[6] + acc[7]));
  bf16 h = (bf16)s;
  wcThi[j * 256 + i] = h;  // wcT[n=j][k=i]
  wcTlo[j * 256 + i] = (bf16)(s - (float)h);
  if (i == 0) {
    float bacc[8] = {};
    for (int k0 = 0; k0 < 256; k0 += 8) {
#pragma unroll
      for (int t = 0; t < 8; ++t)
        bacc[t] = fmaf(bv[k0 + t], Wo[(k0 + t) * 256 + j], bacc[t]);
    }
    bc[j] = ((bacc[0] + bacc[1]) + (bacc[2] + bacc[3])) +
            ((bacc[4] + bacc[5]) + (bacc[6] + bacc[7])) + bo[j];
  }
}

// ---------------------------------------------------------------------------
// gemm3: three independent projections in one launch, XCD-swizzled so the 4
// N-blocks sharing one A row-block have linear ids spaced 8 apart.
// y=0: q (split store)  y=1: k (split store)  y=2: u (bf16, [b][n][L])
// grid (256, 3), block 256 (4 waves; wave = 32 rows x 64 cols)
// ---------------------------------------------------------------------------
__global__ __launch_bounds__(256) void gemm3(
    const float* __restrict__ query, const float* __restrict__ key,
    const float* __restrict__ value,
    const bf16* __restrict__ wqThi, const bf16* __restrict__ wqTlo,
    const bf16* __restrict__ wkThi, const bf16* __restrict__ wkTlo,
    const bf16* __restrict__ wcThi, const bf16* __restrict__ wcTlo,
    const float* __restrict__ bq, const float* __restrict__ bk,
    const float* __restrict__ bc,
    bf16* __restrict__ qhi, bf16* __restrict__ qlo,
    bf16* __restrict__ khi, bf16* __restrict__ klo, bf16* __restrict__ uT) {
  const float* A; const bf16 *WThi, *WTlo; const float* bias;
  bf16 *Chi, *Clo; int storeT;
  switch (blockIdx.y) {
    case 0: A = query; WThi = wqThi; WTlo = wqTlo; bias = bq; Chi = qhi; Clo = qlo; storeT = 0; break;
    case 1: A = key;   WThi = wkThi; WTlo = wkTlo; bias = bk; Chi = khi; Clo = klo; storeT = 0; break;
    default: A = value; WThi = wcThi; WTlo = wcTlo; bias = bc; Chi = uT; Clo = uT; storeT = 1; break;
  }
  int t = threadIdx.x;
  int wid = t >> 6, lane = t & 63, l15 = lane & 15, quad = lane >> 4;
  int id = blockIdx.x;                       // 0..255
  int mb = (id & 7) | ((id >> 5) << 3);      // 0..63
  int nbi = (id >> 3) & 3;                   // 0..3
  int mw = mb * 128 + wid * 32;
  int nb = nbi * 64;

  f32x4 acc[2][4] = {};
  const float* a0p = A + (size_t)(mw + l15) * 256 + quad * 8;
  const float* a1p = a0p + 16 * 256;

#pragma unroll
  for (int ks = 0; ks < 8; ++ks) {
    int kb = ks * 32;
    bf16x8 a0h, a0l, a1h, a1l;
    split8(a0p + kb, a0h, a0l);
    split8(a1p + kb, a1h, a1l);
#pragma unroll
    for (int nt = 0; nt < 4; ++nt) {
      size_t woff = (size_t)(nb + nt * 16 + l15) * 256 + kb + quad * 8;
      bf16x8 wh = *(const bf16x8*)(WThi + woff);
      bf16x8 wl = *(const bf16x8*)(WTlo + woff);
      acc[0][nt] = MFMA16(a0l, wh, MFMA16(a0h, wl, MFMA16(a0h, wh, acc[0][nt])));
      acc[1][nt] = MFMA16(a1l, wh, MFMA16(a1h, wl, MFMA16(a1h, wh, acc[1][nt])));
    }
  }

#pragma unroll
  for (int nt = 0; nt < 4; ++nt) {
    int n = nb + nt * 16 + l15;
    float bvv = bias[n];
#pragma unroll
    for (int mt = 0; mt < 2; ++mt) {
      int mbase = mw + mt * 16 + quad * 4;
      if (!storeT) {
#pragma unroll
        for (int r = 0; r < 4; ++r) {
          float v = acc[mt][nt][r] + bvv;
          bf16 h = (bf16)v;
          Chi[(size_t)(mbase + r) * 256 + n] = h;
          Clo[(size_t)(mbase + r) * 256 + n] = (bf16)(v - (float)h);
        }
      } else {
        int b = mbase >> 12;
        int l = mbase & (L_ - 1);
        bf16x4 pv;
#pragma unroll
        for (int r = 0; r < 4; ++r) pv[r] = (bf16)(acc[mt][nt][r] + bvv);
        *(bf16x4*)(Chi + ((size_t)b * 256 + n) * L_ + l) = pv;
      }
    }
  }
}

// ---------------------------------------------------------------------------
// attn_band: one block = 16 query rows. Band scores (split QK^T) -> softmax
// -> band write (f32) + PV -> out. Zeros already written by prep_zero.
// grid (L/16, B), block 256 (4 waves), 2 blocks/CU.
// ---------------------------------------------------------------------------
__global__ __launch_bounds__(256, 2) void attn_band(
    const bf16* __restrict__ qhi, const bf16* __restrict__ qlo,
    const bf16* __restrict__ khi, const bf16* __restrict__ klo,
    const bf16* __restrict__ uT, float* __restrict__ attn,
    float* __restrict__ out) {
  const int t = threadIdx.x;
  const int bx = blockIdx.x, b = blockIdx.y;
  const int i0 = bx * 16;
  int wid = t >> 6, lane = t & 63, l15 = lane & 15, quad = lane >> 4;

  int jlo = imax(0, i0 - W_);
  int jhi = imin(L_, i0 + 16 + W_);
  int span = jhi - jlo;                // multiple of 16, <= 272
  int spanp = (span + 31) & ~31;       // <= 288
  int nch = span >> 4;                 // 16-col chunks

  __shared__ float sc[16][292];

  // ---- 1) band scores, 3-MFMA split product; q fragments hoisted
  bf16x8 qh[8], ql[8];
  {
    size_t q0 = (size_t)(b * L_ + i0 + l15) * 256 + quad * 8;
#pragma unroll
    for (int ks = 0; ks < 8; ++ks) {
      qh[ks] = *(const bf16x8*)(qhi + q0 + ks * 32);
      ql[ks] = *(const bf16x8*)(qlo + q0 + ks * 32);
    }
  }
  for (int c = wid; c < nch; c += 4) {
    int jb = jlo + c * 16;
    size_t k0 = (size_t)(b * L_ + jb + l15) * 256 + quad * 8;
    f32x4 acc = {};
#pragma unroll
    for (int ks = 0; ks < 8; ++ks) {
      bf16x8 kh = *(const bf16x8*)(khi + k0 + ks * 32);
      bf16x8 kl = *(const bf16x8*)(klo + k0 + ks * 32);
      acc = MFMA16(ql[ks], kh, MFMA16(qh[ks], kl, MFMA16(qh[ks], kh, acc)));
    }
#pragma unroll
    for (int r = 0; r < 4; ++r) sc[quad * 4 + r][c * 16 + l15] = acc[r];
  }
  __syncthreads();

  // ---- 2) masked softmax, 16 threads per row; zero sc pad cols for PV
  {
    int r = t >> 4, s = t & 15;
    int ig = i0 + r;
    float m = -1e30f;
    for (int jj = s; jj < span; jj += 16) {
      int jg = jlo + jj;
      if (jg >= ig - W_ && jg <= ig + W_) m = fmaxf(m, sc[r][jj]);
    }
#pragma unroll
    for (int off = 1; off < 16; off <<= 1) m = fmaxf(m, __shfl_xor(m, off, 16));
    float sum = 0.f;
    for (int jj = s; jj < span; jj += 16) {
      int jg = jlo + jj;
      bool inb = (jg >= ig - W_ && jg <= ig + W_);
      float p = inb ? __expf(sc[r][jj] - m) : 0.f;
      sc[r][jj] = p;
      sum += p;
    }
#pragma unroll
    for (int off = 1; off < 16; off <<= 1) sum += __shfl_xor(sum, off, 16);
    float inv = 1.f / sum;
    for (int jj = s; jj < span; jj += 16) sc[r][jj] *= inv;
    int pc = span + s;
    if (pc < spanp) sc[r][pc] = 0.f;
  }
  __syncthreads();

  // ---- 3) band write (issued before PV so stores drain under MFMA)
  for (int rr = 0; rr < 16; ++rr) {
    int ig = i0 + rr;
    int slo = imax(0, ig - W_) >> 2;
    int shi = imin(L_ - 1, ig + W_) >> 2;
    float* arow = attn + (size_t)(b * L_ + ig) * L_;
    for (int s = slo + t; s <= shi; s += 256) {
      int j0 = s * 4;
      f32x4 v;
#pragma unroll
      for (int e = 0; e < 4; ++e) {
        int jg = j0 + e;
        bool inb = (jg >= ig - W_) && (jg <= ig + W_);
        v[e] = inb ? sc[rr][imax(jg - jlo, 0)] : 0.f;
      }
      __builtin_nontemporal_store(v, (f32x4*)(arow + j0));
    }
  }

  // ---- 4) PV: out = P @ u  (wave w handles cols [w*64, w*64+64))
  {
    f32x4 acc[4] = {};
    for (int kc = 0; kc < (spanp >> 5); ++kc) {
      int kb = kc * 32 + quad * 8;
      bf16x8 a;
      {
        const f32x4* pp = (const f32x4*)&sc[l15][kb];
        f32x4 lo = pp[0], hi = pp[1];
#pragma unroll
        for (int j = 0; j < 4; ++j) { a[j] = (bf16)lo[j]; a[j + 4] = (bf16)hi[j]; }
      }
#pragma unroll
      for (int nt = 0; nt < 4; ++nt) {
        const bf16* up = uT + ((size_t)b * 256 + wid * 64 + nt * 16 + l15) * L_ + jlo + kb;
        acc[nt] = MFMA16(a, *(const bf16x8*)up, acc[nt]);
      }
    }
#pragma unroll
    for (int nt = 0; nt < 4; ++nt) {
      int n = wid * 64 + nt * 16 + l15;
      int row = i0 + quad * 4;
#pragma unroll
      for (int r = 0; r < 4; ++r)
        out[(size_t)(b * L_ + row + r) * 256 + n] = acc[nt][r];
    }
  }
}

// ---------------------------------------------------------------------------
extern "C" void kernel_launch(void* const* d_in, const int* in_sizes, int n_in,
                              void* d_out, int out_size, void* d_ws, size_t ws_size,
                              hipStream_t stream) {
  (void)in_sizes; (void)n_in; (void)out_size; (void)ws_size;

  const float* query = (const float*)d_in[0];
  const float* key   = (const float*)d_in[1];
  const float* value = (const float*)d_in[2];
  const float* Wq = (const float*)d_in[3];
  const float* bq = (const float*)d_in[4];
  const float* Wk = (const float*)d_in[5];
  const float* bk = (const float*)d_in[6];
  const float* Wv = (const float*)d_in[7];
  const float* bv = (const float*)d_in[8];
  const float* Wo = (const float*)d_in[9];
  const float* bo = (const float*)d_in[10];

  float* out    = (float*)d_out;                 // [B, L, 256] f32
  float* attn_f = out + (size_t)B_ * L_ * D_;    // [B, L, L]   f32

  // ws (~21 MB of ~544 MB): bc + 6 split weight mats + q/k hi/lo + uT (+pad)
  char* ws = (char*)d_ws;
  const size_t WSZ = 256 * 256;
  const size_t MSZ = (size_t)B_ * L_ * D_;
  float* bc = (float*)ws;                    // 1 KB (padded to 4 KB)
  bf16* wqThi = (bf16*)(ws + 4096);
  bf16* wqTlo = wqThi + WSZ;
  bf16* wkThi = wqTlo + WSZ;
  bf16* wkTlo = wkThi + WSZ;
  bf16* wcThi = wkTlo + WSZ;
  bf16* wcTlo = wcThi + WSZ;
  bf16* qhi = wcTlo + WSZ;    // 4 MB
  bf16* qlo = qhi + MSZ;      // 4 MB
  bf16* khi = qlo + MSZ;      // 4 MB
  bf16* klo = khi + MSZ;      // 4 MB
  bf16* uT  = klo + MSZ;      // 4 MB, [b][n][L]; PV reads <=32 elems past the
                              // end with P=0 (poison decodes finite) — inside ws.

  prep_zero<<<2432, 256, 0, stream>>>(Wq, Wk, Wv, Wo, bv, bo,
                                      wqThi, wqTlo, wkThi, wkTlo, wcThi, wcTlo,
                                      bc, attn_f);
  gemm3<<<dim3(256, 3), 256, 0, stream>>>(query, key, value,
                                          wqThi, wqTlo, wkThi, wkTlo, wcThi, wcTlo,
                                          bq, bk, bc, qhi, qlo, khi, klo, uT);
  attn_band<<<dim3(L_ / 16, B_), 256, 0, stream>>>(qhi, qlo, khi, klo, uT, attn_f, out);
}

// Round 11
// 262.900 us; speedup vs baseline: 1.0403x; 1.0403x over previous
//
#include <hip/hip_runtime.h>

#define B_ 2
#define L_ 4096
#define D_ 256
#define W_ 128

typedef __bf16 bf16;
typedef __bf16 bf16x8 __attribute__((ext_vector_type(8)));
typedef __bf16 bf16x4 __attribute__((ext_vector_type(4)));
typedef float f32x4 __attribute__((ext_vector_type(4)));

#define MFMA16(a, b, c) __builtin_amdgcn_mfma_f32_16x16x32_bf16((a), (b), (c), 0, 0, 0)

__device__ __forceinline__ int imin(int a, int b) { return a < b ? a : b; }
__device__ __forceinline__ int imax(int a, int b) { return a > b ? a : b; }

// Split 8 consecutive f32 into hi/lo bf16 fragments (hi = rn(x), lo = rn(x-hi)).
__device__ __forceinline__ void split8(const float* p, bf16x8& hi, bf16x8& lo) {
  f32x4 v0 = ((const f32x4*)p)[0], v1 = ((const f32x4*)p)[1];
#pragma unroll
  for (int j = 0; j < 4; ++j) {
    bf16 h0 = (bf16)v0[j]; hi[j] = h0; lo[j] = (bf16)(v0[j] - (float)h0);
    bf16 h1 = (bf16)v1[j]; hi[j + 4] = h1; lo[j + 4] = (bf16)(v1[j] - (float)h1);
  }
}

// ---------------------------------------------------------------------------
// prep_w: 384 blocks x 256 threads.
//   [0,64)    transpose-split Wq     [64,128) transpose-split Wk
//   [128,384) row i of Wc = Wv@Wo (f32, 8-way ILP), stored transposed-split;
//             block i==0 also computes bc = bv@Wo + bo.
// ---------------------------------------------------------------------------
__global__ __launch_bounds__(256) void prep_w(
    const float* __restrict__ Wq, const float* __restrict__ Wk,
    const float* __restrict__ Wv, const float* __restrict__ Wo,
    const float* __restrict__ bv, const float* __restrict__ bo,
    bf16* __restrict__ wqThi, bf16* __restrict__ wqTlo,
    bf16* __restrict__ wkThi, bf16* __restrict__ wkTlo,
    bf16* __restrict__ wcThi, bf16* __restrict__ wcTlo,
    float* __restrict__ bc) {
  int blk = blockIdx.x;
  if (blk < 128) {
    int m = blk >> 6;  // 0: Wq, 1: Wk
    int t = blk & 63;
    int bx = t & 7, by = t >> 3;
    const float* src = m ? Wk : Wq;
    bf16* dh = m ? wkThi : wqThi;
    bf16* dl = m ? wkTlo : wqTlo;
    __shared__ float s[32][33];
    int c = threadIdx.x & 31, r0 = threadIdx.x >> 5;
    int br = by * 32, bcc = bx * 32;
    for (int rr = r0; rr < 32; rr += 8) s[rr][c] = src[(br + rr) * 256 + bcc + c];
    __syncthreads();
    for (int rr = r0; rr < 32; rr += 8) {
      float v = s[c][rr];
      bf16 h = (bf16)v;
      dh[(bcc + rr) * 256 + br + c] = h;
      dl[(bcc + rr) * 256 + br + c] = (bf16)(v - (float)h);
    }
    return;
  }
  int i = blk - 128, j = threadIdx.x;
  float acc[8] = {};
  for (int k0 = 0; k0 < 256; k0 += 8) {
#pragma unroll
    for (int t = 0; t < 8; ++t)
      acc[t] = fmaf(Wv[i * 256 + k0 + t], Wo[(k0 + t) * 256 + j], acc[t]);
  }
  float s = ((acc[0] + acc[1]) + (acc[2] + acc[3])) + ((acc[4] + acc[5]) + (acc[6] + acc[7]));
  bf16 h = (bf16)s;
  wcThi[j * 256 + i] = h;  // wcT[n=j][k=i]
  wcTlo[j * 256 + i] = (bf16)(s - (float)h);
  if (i == 0) {
    float bacc[8] = {};
    for (int k0 = 0; k0 < 256; k0 += 8) {
#pragma unroll
      for (int t = 0; t < 8; ++t)
        bacc[t] = fmaf(bv[k0 + t], Wo[(k0 + t) * 256 + j], bacc[t]);
    }
    bc[j] = ((bacc[0] + bacc[1]) + (bacc[2] + bacc[3])) +
            ((bacc[4] + bacc[5]) + (bacc[6] + bacc[7])) + bo[j];
  }
}

// ---------------------------------------------------------------------------
// gemm3: three independent projections in one launch, XCD-swizzled so the 4
// N-blocks sharing one A row-block have linear ids spaced 8 apart (same XCD
// under round-robin dispatch) -> A re-reads hit that XCD's L2.
// y=0: q (split store)  y=1: k (split store)  y=2: u (bf16, [b][n][L])
// grid (256, 3), block 256 (4 waves; wave = 32 rows x 64 cols)
// ---------------------------------------------------------------------------
__global__ __launch_bounds__(256) void gemm3(
    const float* __restrict__ query, const float* __restrict__ key,
    const float* __restrict__ value,
    const bf16* __restrict__ wqThi, const bf16* __restrict__ wqTlo,
    const bf16* __restrict__ wkThi, const bf16* __restrict__ wkTlo,
    const bf16* __restrict__ wcThi, const bf16* __restrict__ wcTlo,
    const float* __restrict__ bq, const float* __restrict__ bk,
    const float* __restrict__ bc,
    bf16* __restrict__ qhi, bf16* __restrict__ qlo,
    bf16* __restrict__ khi, bf16* __restrict__ klo, bf16* __restrict__ uT) {
  const float* A; const bf16 *WThi, *WTlo; const float* bias;
  bf16 *Chi, *Clo; int storeT;
  switch (blockIdx.y) {
    case 0: A = query; WThi = wqThi; WTlo = wqTlo; bias = bq; Chi = qhi; Clo = qlo; storeT = 0; break;
    case 1: A = key;   WThi = wkThi; WTlo = wkTlo; bias = bk; Chi = khi; Clo = klo; storeT = 0; break;
    default: A = value; WThi = wcThi; WTlo = wcTlo; bias = bc; Chi = uT; Clo = uT; storeT = 1; break;
  }
  int t = threadIdx.x;
  int wid = t >> 6, lane = t & 63, l15 = lane & 15, quad = lane >> 4;
  int id = blockIdx.x;                       // 0..255
  int mb = (id & 7) | ((id >> 5) << 3);      // 0..63
  int nbi = (id >> 3) & 3;                   // 0..3
  int mw = mb * 128 + wid * 32;
  int nb = nbi * 64;

  f32x4 acc[2][4] = {};
  const float* a0p = A + (size_t)(mw + l15) * 256 + quad * 8;
  const float* a1p = a0p + 16 * 256;

#pragma unroll
  for (int ks = 0; ks < 8; ++ks) {
    int kb = ks * 32;
    bf16x8 a0h, a0l, a1h, a1l;
    split8(a0p + kb, a0h, a0l);
    split8(a1p + kb, a1h, a1l);
#pragma unroll
    for (int nt = 0; nt < 4; ++nt) {
      size_t woff = (size_t)(nb + nt * 16 + l15) * 256 + kb + quad * 8;
      bf16x8 wh = *(const bf16x8*)(WThi + woff);
      bf16x8 wl = *(const bf16x8*)(WTlo + woff);
      acc[0][nt] = MFMA16(a0l, wh, MFMA16(a0h, wl, MFMA16(a0h, wh, acc[0][nt])));
      acc[1][nt] = MFMA16(a1l, wh, MFMA16(a1h, wl, MFMA16(a1h, wh, acc[1][nt])));
    }
  }

#pragma unroll
  for (int nt = 0; nt < 4; ++nt) {
    int n = nb + nt * 16 + l15;
    float bvv = bias[n];
#pragma unroll
    for (int mt = 0; mt < 2; ++mt) {
      int mbase = mw + mt * 16 + quad * 4;
      if (!storeT) {
#pragma unroll
        for (int r = 0; r < 4; ++r) {
          float v = acc[mt][nt][r] + bvv;
          bf16 h = (bf16)v;
          Chi[(size_t)(mbase + r) * 256 + n] = h;
          Clo[(size_t)(mbase + r) * 256 + n] = (bf16)(v - (float)h);
        }
      } else {
        int b = mbase >> 12;
        int l = mbase & (L_ - 1);
        bf16x4 pv;
#pragma unroll
        for (int r = 0; r < 4; ++r) pv[r] = (bf16)(acc[mt][nt][r] + bvv);
        *(bf16x4*)(Chi + ((size_t)b * 256 + n) * L_ + l) = pv;
      }
    }
  }
}

// ---------------------------------------------------------------------------
// attn_fused: one block = 16 query rows. grid (256, B) = 512 blocks = 2/CU.
// Phase parity stagger ((bx^by)&1): even blocks write zero-slots first (store
// drain overlaps co-resident odd block's MFMA), odd blocks write them last.
// ---------------------------------------------------------------------------
__global__ __launch_bounds__(256, 2) void attn_fused(
    const bf16* __restrict__ qhi, const bf16* __restrict__ qlo,
    const bf16* __restrict__ khi, const bf16* __restrict__ klo,
    const bf16* __restrict__ uT, float* __restrict__ attn,
    float* __restrict__ out) {
  const int tid = threadIdx.x;
  const int bx = blockIdx.x, b = blockIdx.y;
  const int i0 = bx * 16;
  int wid = tid >> 6, lane = tid & 63, l15 = lane & 15, quad = lane >> 4;

  int jlo = imax(0, i0 - W_);
  int jhi = imin(L_, i0 + 16 + W_);
  int span = jhi - jlo;                // multiple of 16, <= 272
  int spanp = (span + 31) & ~31;       // <= 288
  int nch = span >> 4;                 // 16-col chunks

  __shared__ float sc[16][292];

  bool early = ((bx ^ b) & 1) == 0;

  // zero-slot writer: all 16B slots fully outside the band
  auto write_zeros = [&]() {
    for (int idx = tid; idx < 16 * 1024; idx += 256) {
      int rr = idx >> 10, s = idx & 1023;
      int ig = i0 + rr;
      int slo = imax(0, ig - W_) >> 2;
      int shi = imin(L_ - 1, ig + W_) >> 2;
      if (s < slo || s > shi) {
        f32x4 z = {0.f, 0.f, 0.f, 0.f};
        __builtin_nontemporal_store(z, (f32x4*)(attn + (size_t)(b * L_ + ig) * L_ + s * 4));
      }
    }
  };
  if (early) write_zeros();

  // ---- 1) band scores, 3-MFMA split product; q fragments hoisted
  bf16x8 qh[8], ql[8];
  {
    size_t q0 = (size_t)(b * L_ + i0 + l15) * 256 + quad * 8;
#pragma unroll
    for (int ks = 0; ks < 8; ++ks) {
      qh[ks] = *(const bf16x8*)(qhi + q0 + ks * 32);
      ql[ks] = *(const bf16x8*)(qlo + q0 + ks * 32);
    }
  }
  for (int c = wid; c < nch; c += 4) {
    int jb = jlo + c * 16;
    size_t k0 = (size_t)(b * L_ + jb + l15) * 256 + quad * 8;
    f32x4 acc = {};
#pragma unroll
    for (int ks = 0; ks < 8; ++ks) {
      bf16x8 kh = *(const bf16x8*)(khi + k0 + ks * 32);
      bf16x8 kl = *(const bf16x8*)(klo + k0 + ks * 32);
      acc = MFMA16(ql[ks], kh, MFMA16(qh[ks], kl, MFMA16(qh[ks], kh, acc)));
    }
#pragma unroll
    for (int r = 0; r < 4; ++r) sc[quad * 4 + r][c * 16 + l15] = acc[r];
  }
  __syncthreads();

  // ---- 2) masked softmax, 16 threads per row; also zero sc pad cols for PV
  {
    int r = tid >> 4, s = tid & 15;
    int ig = i0 + r;
    float m = -1e30f;
    for (int jj = s; jj < span; jj += 16) {
      int jg = jlo + jj;
      if (jg >= ig - W_ && jg <= ig + W_) m = fmaxf(m, sc[r][jj]);
    }
#pragma unroll
    for (int off = 1; off < 16; off <<= 1) m = fmaxf(m, __shfl_xor(m, off, 16));
    float sum = 0.f;
    for (int jj = s; jj < span; jj += 16) {
      int jg = jlo + jj;
      bool inb = (jg >= ig - W_ && jg <= ig + W_);
      float p = inb ? __expf(sc[r][jj] - m) : 0.f;
      sc[r][jj] = p;
      sum += p;
    }
#pragma unroll
    for (int off = 1; off < 16; off <<= 1) sum += __shfl_xor(sum, off, 16);
    float inv = 1.f / sum;
    for (int jj = s; jj < span; jj += 16) sc[r][jj] *= inv;
    int pc = span + s;
    if (pc < spanp) sc[r][pc] = 0.f;
  }
  __syncthreads();

  // ---- 3) band write (issued before PV so stores drain under MFMA)
  for (int rr = 0; rr < 16; ++rr) {
    int ig = i0 + rr;
    int slo = imax(0, ig - W_) >> 2;
    int shi = imin(L_ - 1, ig + W_) >> 2;
    float* arow = attn + (size_t)(b * L_ + ig) * L_;
    for (int s = slo + tid; s <= shi; s += 256) {
      int j0 = s * 4;
      f32x4 v;
#pragma unroll
      for (int e = 0; e < 4; ++e) {
        int jg = j0 + e;
        bool inb = (jg >= ig - W_) && (jg <= ig + W_);
        v[e] = inb ? sc[rr][imax(jg - jlo, 0)] : 0.f;
      }
      __builtin_nontemporal_store(v, (f32x4*)(arow + j0));
    }
  }

  // ---- 4) PV: out = P @ u  (wave w handles cols [w*64, w*64+64))
  {
    f32x4 acc[4] = {};
    for (int kc = 0; kc < (spanp >> 5); ++kc) {
      int kb = kc * 32 + quad * 8;
      bf16x8 a;
      {
        const f32x4* pp = (const f32x4*)&sc[l15][kb];
        f32x4 lo = pp[0], hi = pp[1];
#pragma unroll
        for (int j = 0; j < 4; ++j) { a[j] = (bf16)lo[j]; a[j + 4] = (bf16)hi[j]; }
      }
#pragma unroll
      for (int nt = 0; nt < 4; ++nt) {
        const bf16* up = uT + ((size_t)b * 256 + wid * 64 + nt * 16 + l15) * L_ + jlo + kb;
        acc[nt] = MFMA16(a, *(const bf16x8*)up, acc[nt]);
      }
    }
#pragma unroll
    for (int nt = 0; nt < 4; ++nt) {
      int n = wid * 64 + nt * 16 + l15;
      int row = i0 + quad * 4;
#pragma unroll
      for (int r = 0; r < 4; ++r)
        out[(size_t)(b * L_ + row + r) * 256 + n] = acc[nt][r];
    }
  }

  if (!early) write_zeros();
}

// ---------------------------------------------------------------------------
extern "C" void kernel_launch(void* const* d_in, const int* in_sizes, int n_in,
                              void* d_out, int out_size, void* d_ws, size_t ws_size,
                              hipStream_t stream) {
  (void)in_sizes; (void)n_in; (void)out_size; (void)ws_size;

  const float* query = (const float*)d_in[0];
  const float* key   = (const float*)d_in[1];
  const float* value = (const float*)d_in[2];
  const float* Wq = (const float*)d_in[3];
  const float* bq = (const float*)d_in[4];
  const float* Wk = (const float*)d_in[5];
  const float* bk = (const float*)d_in[6];
  const float* Wv = (const float*)d_in[7];
  const float* bv = (const float*)d_in[8];
  const float* Wo = (const float*)d_in[9];
  const float* bo = (const float*)d_in[10];

  float* out    = (float*)d_out;                 // [B, L, 256] f32
  float* attn_f = out + (size_t)B_ * L_ * D_;    // [B, L, L]   f32

  // ws (~21 MB of ~544 MB): bc + 6 split weight mats + q/k hi/lo + uT (+pad)
  char* ws = (char*)d_ws;
  const size_t WSZ = 256 * 256;
  const size_t MSZ = (size_t)B_ * L_ * D_;
  float* bc = (float*)ws;                    // 1 KB (padded to 4 KB)
  bf16* wqThi = (bf16*)(ws + 4096);
  bf16* wqTlo = wqThi + WSZ;
  bf16* wkThi = wqTlo + WSZ;
  bf16* wkTlo = wkThi + WSZ;
  bf16* wcThi = wkTlo + WSZ;
  bf16* wcTlo = wcThi + WSZ;
  bf16* qhi = wcTlo + WSZ;    // 4 MB
  bf16* qlo = qhi + MSZ;      // 4 MB
  bf16* khi = qlo + MSZ;      // 4 MB
  bf16* klo = khi + MSZ;      // 4 MB
  bf16* uT  = klo + MSZ;      // 4 MB, [b][n][L]; PV may read <=32 elems past
                              // the end with P=0 (poison decodes finite) — inside ws.

  prep_w<<<384, 256, 0, stream>>>(Wq, Wk, Wv, Wo, bv, bo,
                                  wqThi, wqTlo, wkThi, wkTlo, wcThi, wcTlo, bc);
  gemm3<<<dim3(256, 3), 256, 0, stream>>>(query, key, value,
                                          wqThi, wqTlo, wkThi, wkTlo, wcThi, wcTlo,
                                          bq, bk, bc, qhi, qlo, khi, klo, uT);
  attn_fused<<<dim3(L_ / 16, B_), 256, 0, stream>>>(qhi, qlo, khi, klo, uT, attn_f, out);
}